// Round 10
// baseline (18.426 us; speedup 1.0000x reference)
//
#include <hip/hip_runtime.h>

#define NB 64
#define NA 5
#define NC 20
#define NH 38
#define NW 38
#define MAXT 40
#define CS (NH * NW)                 // 1444
#define CELLS_PER_B (NA * CS)        // 7220
#define TPB 256
#define CPT 2                        // cells per thread
#define CHUNK_CELLS (TPB * CPT)      // 512
#define CHUNKS 16                    // 15 live chunks + 1 winner-only chunk
#define NBLK (NB * CHUNKS)           // 1024 = 4 blocks/CU exactly
#define IOUC (0.4f / 1.4f)           // shared pre-scale for the iou>0.4 test

__constant__ float c_aw[NA] = {1.3221f, 3.19275f, 5.05587f, 9.47112f, 11.2364f};
__constant__ float c_ah[NA] = {1.73145f, 4.00944f, 8.09892f, 4.84053f, 10.0071f};

__device__ __forceinline__ float sl1(float d) {
    d = fabsf(d);
    return (d < 1.0f) ? 0.5f * d * d : d - 0.5f;
}
__device__ __forceinline__ float sigm(float x) {
    return __builtin_amdgcn_rcpf(1.0f + __expf(-x));
}
__device__ __forceinline__ float rdlane(float v, int l) {
    return __int_as_float(__builtin_amdgcn_readlane(__float_as_int(v), l));
}

__global__ __launch_bounds__(TPB) void region_kernel(
    const float* __restrict__ outp, const float* __restrict__ tgt,
    float2* __restrict__ partials)
{
    __shared__ float4 s_box[MAXT];   // winner block only
    __shared__ float  s_ga[MAXT];
    __shared__ int    s_key[MAXT];
    __shared__ float  red[8];

    const int b     = blockIdx.x >> 4;
    const int chunk = blockIdx.x & 15;
    const int tid   = threadIdx.x;
    const int lane  = tid & 63;

    float box_sum = 0.0f, cls_sum = 0.0f;

    if (chunk == CHUNKS - 1) {
        // ================= winner-only block (no live dense cells) =========
        float w_gx = 0.f, w_gy = 0.f, w_gw = 0.f, w_gh = 0.f;
        int   w_bn = 0, w_gi = 0, w_gj = 0, w_cls = 0, mykey = -1;
        bool  w_valid = false;

        if (tid < 64) {
            const bool is_t = tid < MAXT;
            const float* tb = tgt + b * (MAXT * 5) + tid * 5;
            float t0 = 0.f, t1 = 0.f, t2 = 0.f, t3 = 0.f, t4 = 0.f;
            if (is_t) { t0 = tb[0]; t1 = tb[1]; t2 = tb[2]; t3 = tb[3]; t4 = tb[4]; }
            const unsigned long long nz = __ballot(is_t && (t1 != 0.0f));
            const bool valid = is_t && ((~nz & (((1ull << tid) << 1) - 1ull)) == 0ull);
            if (is_t) {
                float4 mybox = make_float4(3e30f, 3e30f, -3e30f, -3e30f);
                float  myga  = 0.0f;
                if (valid) {
                    const float gx = t1 * NW, gy = t2 * NH, gw = t3 * NW, gh = t4 * NH;
                    int bn = 0; float best = -1.0f;
                    #pragma unroll
                    for (int a = 0; a < NA; ++a) {
                        const float inter = fminf(gw, c_aw[a]) * fminf(gh, c_ah[a]);
                        const float aiou  = inter / (gw * gh + c_aw[a] * c_ah[a] - inter);
                        if (aiou > best) { best = aiou; bn = a; }
                    }
                    const int gi = min(max((int)gx, 0), NW - 1);
                    const int gj = min(max((int)gy, 0), NH - 1);
                    mybox = make_float4(gx - 0.5f * gw, gy - 0.5f * gh,
                                        gx + 0.5f * gw, gy + 0.5f * gh);
                    myga  = IOUC * (gw * gh);
                    mykey = bn * CS + gj * NW + gi;
                    w_gx = gx; w_gy = gy; w_gw = gw; w_gh = gh;
                    w_bn = bn; w_gi = gi; w_gj = gj; w_cls = (int)t0; w_valid = true;
                }
                s_box[tid] = mybox; s_ga[tid] = myga; s_key[tid] = valid ? mykey : -1;
            }
        }
        __syncthreads();   // block-uniform path

        if (w_valid) {
            bool last = true;
            for (int tp = tid + 1; tp < MAXT; ++tp) last &= (s_key[tp] != mykey);
            if (last) {
                const float* cell = outp + (size_t)((b * NA + w_bn) * (5 + NC)) * CS
                                    + (w_gj * NW + w_gi);
                const float xw = cell[0],      yw = cell[CS];
                const float ww = cell[2 * CS], hw = cell[3 * CS], cw = cell[4 * CS];
                float cls_v[NC];
                #pragma unroll
                for (int q = 0; q < NC; ++q) cls_v[q] = cell[(5 + q) * CS];

                const float sx = sigm(xw), sy = sigm(yw), sc = sigm(cw);
                const float pxc = sx + (float)w_gi, pyc = sy + (float)w_gj;
                const float pw = __expf(ww) * c_aw[w_bn], ph = __expf(hw) * c_ah[w_bn];
                const float wx1 = pxc - 0.5f * pw, wx2 = pxc + 0.5f * pw;
                const float wy1 = pyc - 0.5f * ph, wy2 = pyc + 0.5f * ph;
                const float pa = pw * ph, wp04 = IOUC * (pw * ph);

                // flag: bitwise-identical formula to the dense pass
                bool flag = false;
                for (int t = 0; t < MAXT; ++t) {
                    const float4 bx = s_box[t];
                    const float iw = fminf(wx2, bx.z) - fmaxf(wx1, bx.x);
                    const float ih = fminf(wy2, bx.w) - fmaxf(wy1, bx.y);
                    const float inter = fmaxf(iw, 0.0f) * fmaxf(ih, 0.0f);
                    flag = flag | (inter > wp04 + s_ga[t]);
                }
                const float cmd = flag ? 0.0f : 1.0f;

                const float gx1 = w_gx - 0.5f * w_gw, gx2 = w_gx + 0.5f * w_gw;
                const float gy1 = w_gy - 0.5f * w_gh, gy2 = w_gy + 0.5f * w_gh;
                const float iw = fminf(wx2, gx2) - fmaxf(wx1, gx1);
                const float ih = fminf(wy2, gy2) - fmaxf(wy1, gy1);
                const float inter = fmaxf(iw, 0.f) * fmaxf(ih, 0.f);
                const float tconf = inter / (w_gw * w_gh + pa - inter);

                const float dc = sc - tconf;
                box_sum += 2.5f * dc * dc - 0.5f * cmd * sc * sc;

                const float vtx = w_gx - (float)w_gi, vty = w_gy - (float)w_gj;
                const float vtw = __logf(w_gw / c_aw[w_bn]);
                const float vth = __logf(w_gh / c_ah[w_bn]);
                box_sum += 0.5f * (sl1(sx - vtx) + sl1(sy - vty) +
                                   sl1(ww - vtw) + sl1(hw - vth));

                float m = -1e30f;
                #pragma unroll
                for (int q = 0; q < NC; ++q) m = fmaxf(m, cls_v[q]);
                float se = 0.f, lt = 0.f;
                #pragma unroll
                for (int q = 0; q < NC; ++q) {
                    se += __expf(cls_v[q] - m);
                    if (q == w_cls) lt = cls_v[q];
                }
                const float logpt = lt - (m + __logf(se));
                const float pt = __expf(logpt);
                const float om = 1.0f - pt;
                cls_sum += -(om * om) * logpt;
            }
        }
    } else {
        // ================= dense block: no LDS, no barrier =================
        // 1) issue cell loads first
        const int cbase = chunk * CHUNK_CELLS + tid;
        float xo[CPT], yo[CPT], wo[CPT], ho[CPT], co[CPT];
        bool live[CPT];
        #pragma unroll
        for (int u = 0; u < CPT; ++u) {
            const int c  = cbase + u * TPB;
            live[u] = (c < CELLS_PER_B);
            const int cc = live[u] ? c : (CELLS_PER_B - 1);
            const int a  = cc / CS, r = cc - a * CS;
            const float* cell = outp + (size_t)((b * NA + a) * (5 + NC)) * CS + r;
            xo[u] = cell[0];      yo[u] = cell[CS];
            wo[u] = cell[2 * CS]; ho[u] = cell[3 * CS];
            co[u] = cell[4 * CS];
        }

        // 2) per-wave target table: lane t owns target t (no LDS, no barrier)
        float x1v = 3e30f, y1v = 3e30f, x2v = -3e30f, y2v = -3e30f, gav = 0.0f;
        {
            const bool is_t = lane < MAXT;
            const float* tb = tgt + b * (MAXT * 5) + lane * 5;
            float t1 = 0.f, t2 = 0.f, t3 = 0.f, t4 = 0.f;
            if (is_t) { t1 = tb[1]; t2 = tb[2]; t3 = tb[3]; t4 = tb[4]; }
            const unsigned long long nz = __ballot(is_t && (t1 != 0.0f));
            const bool valid = is_t && ((~nz & (((1ull << lane) << 1) - 1ull)) == 0ull);
            if (valid) {
                const float gx = t1 * NW, gy = t2 * NH, gw = t3 * NW, gh = t4 * NH;
                x1v = gx - 0.5f * gw; y1v = gy - 0.5f * gh;
                x2v = gx + 0.5f * gw; y2v = gy + 0.5f * gh;
                gav = IOUC * (gw * gh);
            }
        }

        // 3) per-cell preprocessing
        float px1[CPT], px2[CPT], py1[CPT], py2[CPT], p04[CPT], scv[CPT];
        #pragma unroll
        for (int u = 0; u < CPT; ++u) {
            const int c = cbase + u * TPB;
            const int cc = live[u] ? c : 0;
            const int a = cc / CS, r = cc - a * CS;
            const int j = r / NW,  i = r - j * NW;
            const float sx = sigm(xo[u]), sy = sigm(yo[u]);
            scv[u] = live[u] ? sigm(co[u]) : 0.0f;   // dead cells contribute 0
            const float pxc = sx + (float)i, pyc = sy + (float)j;
            const float pw = __expf(wo[u]) * c_aw[a], ph = __expf(ho[u]) * c_ah[a];
            px1[u] = pxc - 0.5f * pw; px2[u] = pxc + 0.5f * pw;
            py1[u] = pyc - 0.5f * ph; py2[u] = pyc + 0.5f * ph;
            p04[u] = IOUC * (pw * ph);
        }

        // 4) hot loop: v_readlane broadcast (VALU pipe), no LDS
        bool flag[CPT];
        #pragma unroll
        for (int u = 0; u < CPT; ++u) flag[u] = false;

        #pragma unroll
        for (int t = 0; t < MAXT; ++t) {
            const float bx1 = rdlane(x1v, t);
            const float by1 = rdlane(y1v, t);
            const float bx2 = rdlane(x2v, t);
            const float by2 = rdlane(y2v, t);
            const float ga  = rdlane(gav, t);
            #pragma unroll
            for (int u = 0; u < CPT; ++u) {
                const float iw = fminf(px2[u], bx2) - fmaxf(px1[u], bx1);
                const float ih = fminf(py2[u], by2) - fmaxf(py1[u], by1);
                const float inter = fmaxf(iw, 0.0f) * fmaxf(ih, 0.0f);
                flag[u] = flag[u] | (inter > p04[u] + ga);
            }
        }

        #pragma unroll
        for (int u = 0; u < CPT; ++u) {
            if (!flag[u]) box_sum += 0.5f * scv[u] * scv[u];
        }
    }

    // ---- block reduction -> one float2 per block ----
    #pragma unroll
    for (int off = 32; off > 0; off >>= 1) {
        box_sum += __shfl_down(box_sum, off);
        cls_sum += __shfl_down(cls_sum, off);
    }
    const int wv = tid >> 6, ln = tid & 63;
    if (ln == 0) { red[wv] = box_sum; red[4 + wv] = cls_sum; }
    __syncthreads();
    if (tid == 0) {
        partials[blockIdx.x] = make_float2(red[0] + red[1] + red[2] + red[3],
                                           red[4] + red[5] + red[6] + red[7]);
    }
}

__global__ __launch_bounds__(256) void finalize_kernel(
    const float2* __restrict__ partials, float* __restrict__ o)
{
    const int tid = threadIdx.x;
    float box = 0.0f, cls = 0.0f;
    #pragma unroll
    for (int k = 0; k < 4; ++k) {                 // NBLK == 1024
        const float2 p = partials[tid + k * 256];
        box += p.x; cls += p.y;
    }
    #pragma unroll
    for (int off = 32; off > 0; off >>= 1) {
        box += __shfl_down(box, off);
        cls += __shfl_down(cls, off);
    }
    __shared__ float red[8];
    const int wv = tid >> 6, ln = tid & 63;
    if (ln == 0) { red[wv] = box; red[4 + wv] = cls; }
    __syncthreads();
    if (tid == 0) {
        const float boxT = red[0] + red[1] + red[2] + red[3];
        const float clsT = red[4] + red[5] + red[6] + red[7];
        o[0] = boxT + clsT;   // loss
        o[1] = clsT;          // loss_cls
        o[2] = boxT;          // loss_box
    }
}

extern "C" void kernel_launch(void* const* d_in, const int* in_sizes, int n_in,
                              void* d_out, int out_size, void* d_ws, size_t ws_size,
                              hipStream_t stream)
{
    const float* outp = (const float*)d_in[0];
    const float* tgt  = (const float*)d_in[1];
    float2* partials  = (float2*)d_ws;    // 1024 * 8 B, fully rewritten every call

    region_kernel<<<dim3(NBLK), dim3(TPB), 0, stream>>>(outp, tgt, partials);
    finalize_kernel<<<1, 256, 0, stream>>>(partials, (float*)d_out);
}

// Round 11
// 17.789 us; speedup vs baseline: 1.0358x; 1.0358x over previous
//
#include <hip/hip_runtime.h>

#define NB 64
#define NA 5
#define NC 20
#define NH 38
#define NW 38
#define MAXT 40
#define CS (NH * NW)                 // 1444
#define CELLS_PER_B (NA * CS)        // 7220
#define TPB 256
#define CPT 2                        // cells per thread
#define CHUNK_CELLS (TPB * CPT)      // 512
#define CHUNKS 16                    // 15 live chunks + 1 winner-only chunk
#define NBLK (NB * CHUNKS)           // 1024 = 4 blocks/CU exactly
#define IOUC (0.4f / 1.4f)           // shared pre-scale for the iou>0.4 test

__constant__ float c_aw[NA] = {1.3221f, 3.19275f, 5.05587f, 9.47112f, 11.2364f};
__constant__ float c_ah[NA] = {1.73145f, 4.00944f, 8.09892f, 4.84053f, 10.0071f};

__device__ __forceinline__ float sl1(float d) {
    d = fabsf(d);
    return (d < 1.0f) ? 0.5f * d * d : d - 0.5f;
}
__device__ __forceinline__ float sigm(float x) {
    return __builtin_amdgcn_rcpf(1.0f + __expf(-x));
}

__global__ __launch_bounds__(TPB) void region_kernel(
    const float* __restrict__ outp, const float* __restrict__ tgt,
    float2* __restrict__ partials)
{
    __shared__ float4 s_box[MAXT];
    __shared__ alignas(16) float s_ga[MAXT];   // (0.4/1.4) * gw * gh
    __shared__ int    s_key[MAXT];

    const int b     = blockIdx.x >> 4;
    const int chunk = blockIdx.x & 15;
    const int tid   = threadIdx.x;

    // ---- 1) issue dense cell loads FIRST (latency hides under prologue) ----
    const int cbase = chunk * CHUNK_CELLS + tid;
    float xo[CPT], yo[CPT], wo[CPT], ho[CPT], co[CPT];
    bool live[CPT];
    #pragma unroll
    for (int u = 0; u < CPT; ++u) {
        const int c  = cbase + u * TPB;
        live[u] = (c < CELLS_PER_B);
        const int cc = live[u] ? c : (CELLS_PER_B - 1);   // clamp: uniform loads
        const int a  = cc / CS, r = cc - a * CS;
        const float* cell = outp + (size_t)((b * NA + a) * (5 + NC)) * CS + r;
        xo[u] = cell[0];      yo[u] = cell[CS];
        wo[u] = cell[2 * CS]; ho[u] = cell[3 * CS];
        co[u] = cell[4 * CS];
    }

    // ---- 2) per-target prep: wave 0, ballot cumprod ----
    float w_gx = 0.f, w_gy = 0.f, w_gw = 0.f, w_gh = 0.f;
    int   w_bn = 0, w_gi = 0, w_gj = 0, w_cls = 0, mykey = -1;
    bool  w_valid = false;

    if (tid < 64) {
        const bool is_t = tid < MAXT;
        const float* tb = tgt + b * (MAXT * 5) + tid * 5;
        float t0 = 0.f, t1 = 0.f, t2 = 0.f, t3 = 0.f, t4 = 0.f;
        if (is_t) { t0 = tb[0]; t1 = tb[1]; t2 = tb[2]; t3 = tb[3]; t4 = tb[4]; }
        const unsigned long long nz = __ballot(is_t && (t1 != 0.0f));
        const bool valid = is_t && ((~nz & (((1ull << tid) << 1) - 1ull)) == 0ull);
        if (is_t) {
            float4 mybox = make_float4(3e30f, 3e30f, -3e30f, -3e30f); // inter -> 0
            float  myga  = 0.0f;
            if (valid) {
                const float gx = t1 * NW, gy = t2 * NH, gw = t3 * NW, gh = t4 * NH;
                int bn = 0; float best = -1.0f;
                #pragma unroll
                for (int a = 0; a < NA; ++a) {
                    const float inter = fminf(gw, c_aw[a]) * fminf(gh, c_ah[a]);
                    const float aiou  = inter / (gw * gh + c_aw[a] * c_ah[a] - inter);
                    if (aiou > best) { best = aiou; bn = a; }
                }
                const int gi = min(max((int)gx, 0), NW - 1);
                const int gj = min(max((int)gy, 0), NH - 1);
                mybox = make_float4(gx - 0.5f * gw, gy - 0.5f * gh,
                                    gx + 0.5f * gw, gy + 0.5f * gh);
                myga  = IOUC * (gw * gh);
                mykey = bn * CS + gj * NW + gi;
                w_gx = gx; w_gy = gy; w_gw = gw; w_gh = gh;
                w_bn = bn; w_gi = gi; w_gj = gj; w_cls = (int)t0; w_valid = true;
            }
            s_box[tid] = mybox; s_ga[tid] = myga; s_key[tid] = valid ? mykey : -1;
        }
    }

    // ---- 3) per-cell preprocessing (no LDS dependency -> before barrier) ----
    float px1[CPT], px2[CPT], py1[CPT], py2[CPT], p04[CPT], scv[CPT];
    #pragma unroll
    for (int u = 0; u < CPT; ++u) {
        const int c = cbase + u * TPB;
        const int cc = live[u] ? c : 0;
        const int a = cc / CS, r = cc - a * CS;
        const int j = r / NW,  i = r - j * NW;
        const float sx = sigm(xo[u]), sy = sigm(yo[u]);
        scv[u] = live[u] ? sigm(co[u]) : 0.0f;    // dead cells contribute 0
        const float pxc = sx + (float)i, pyc = sy + (float)j;
        const float pw = __expf(wo[u]) * c_aw[a], ph = __expf(ho[u]) * c_ah[a];
        px1[u] = pxc - 0.5f * pw; px2[u] = pxc + 0.5f * pw;
        py1[u] = pyc - 0.5f * ph; py2[u] = pyc + 0.5f * ph;
        p04[u] = IOUC * (pw * ph);
    }

    __syncthreads();

    float box_sum = 0.0f, cls_sum = 0.0f;

    // ---- 4) winner pass: dedicated winner-only chunk (no dense cells) ----
    if (chunk == CHUNKS - 1 && w_valid) {
        bool last = true;
        for (int tp = tid + 1; tp < MAXT; ++tp) last &= (s_key[tp] != mykey);
        if (last) {
            const float* cell = outp + (size_t)((b * NA + w_bn) * (5 + NC)) * CS
                                + (w_gj * NW + w_gi);
            const float xw = cell[0],      yw = cell[CS];
            const float ww = cell[2 * CS], hw = cell[3 * CS], cw = cell[4 * CS];
            float cls_v[NC];
            #pragma unroll
            for (int q = 0; q < NC; ++q) cls_v[q] = cell[(5 + q) * CS];

            const float sx = sigm(xw), sy = sigm(yw), sc = sigm(cw);
            const float pxc = sx + (float)w_gi, pyc = sy + (float)w_gj;
            const float pw = __expf(ww) * c_aw[w_bn], ph = __expf(hw) * c_ah[w_bn];
            const float wx1 = pxc - 0.5f * pw, wx2 = pxc + 0.5f * pw;
            const float wy1 = pyc - 0.5f * ph, wy2 = pyc + 0.5f * ph;
            const float pa = pw * ph, wp04 = IOUC * (pw * ph);

            // flag: bitwise-identical formula to the dense pass
            bool flag = false;
            for (int t = 0; t < MAXT; ++t) {
                const float4 bx = s_box[t];
                const float iw = fminf(wx2, bx.z) - fmaxf(wx1, bx.x);
                const float ih = fminf(wy2, bx.w) - fmaxf(wy1, bx.y);
                const float inter = fmaxf(iw, 0.0f) * fmaxf(ih, 0.0f);
                flag = flag | (inter > wp04 + s_ga[t]);
            }
            const float cmd = flag ? 0.0f : 1.0f;

            // tconf = IoU(own gt, pred), exact divide
            const float gx1 = w_gx - 0.5f * w_gw, gx2 = w_gx + 0.5f * w_gw;
            const float gy1 = w_gy - 0.5f * w_gh, gy2 = w_gy + 0.5f * w_gh;
            const float iw = fminf(wx2, gx2) - fmaxf(wx1, gx1);
            const float ih = fminf(wy2, gy2) - fmaxf(wy1, gy1);
            const float inter = fmaxf(iw, 0.f) * fmaxf(ih, 0.f);
            const float tconf = inter / (w_gw * w_gh + pa - inter);

            const float dc = sc - tconf;
            box_sum += 2.5f * dc * dc - 0.5f * cmd * sc * sc;  // winner - dense term

            const float vtx = w_gx - (float)w_gi, vty = w_gy - (float)w_gj;
            const float vtw = __logf(w_gw / c_aw[w_bn]);
            const float vth = __logf(w_gh / c_ah[w_bn]);
            box_sum += 0.5f * (sl1(sx - vtx) + sl1(sy - vty) +
                               sl1(ww - vtw) + sl1(hw - vth));

            float m = -1e30f;
            #pragma unroll
            for (int q = 0; q < NC; ++q) m = fmaxf(m, cls_v[q]);
            float se = 0.f, lt = 0.f;
            #pragma unroll
            for (int q = 0; q < NC; ++q) {
                se += __expf(cls_v[q] - m);
                if (q == w_cls) lt = cls_v[q];
            }
            const float logpt = lt - (m + __logf(se));
            const float pt = __expf(logpt);
            const float om = 1.0f - pt;
            cls_sum += -(om * om) * logpt;
        }
    } else if (chunk != CHUNKS - 1) {
        // ---- 5) dense hot loop (block-uniform skip for the winner chunk) ----
        bool flag[CPT];
        #pragma unroll
        for (int u = 0; u < CPT; ++u) flag[u] = false;

        #pragma unroll 2
        for (int t4 = 0; t4 < MAXT; t4 += 4) {
            const float4 ga4 = *reinterpret_cast<const float4*>(&s_ga[t4]);
            #pragma unroll
            for (int k = 0; k < 4; ++k) {
                const float4 bx = s_box[t4 + k];
                const float  ga = (k == 0) ? ga4.x : (k == 1) ? ga4.y
                                 : (k == 2) ? ga4.z : ga4.w;
                #pragma unroll
                for (int u = 0; u < CPT; ++u) {
                    const float iw = fminf(px2[u], bx.z) - fmaxf(px1[u], bx.x);
                    const float ih = fminf(py2[u], bx.w) - fmaxf(py1[u], bx.y);
                    const float inter = fmaxf(iw, 0.0f) * fmaxf(ih, 0.0f);
                    flag[u] = flag[u] | (inter > p04[u] + ga);
                }
            }
        }

        #pragma unroll
        for (int u = 0; u < CPT; ++u) {
            if (!flag[u]) box_sum += 0.5f * scv[u] * scv[u];
        }
    }

    // ---- 6) block reduction -> one float2 per block ----
    #pragma unroll
    for (int off = 32; off > 0; off >>= 1) {
        box_sum += __shfl_down(box_sum, off);
        cls_sum += __shfl_down(cls_sum, off);
    }
    __shared__ float red[8];
    const int wv = tid >> 6, ln = tid & 63;
    if (ln == 0) { red[wv] = box_sum; red[4 + wv] = cls_sum; }
    __syncthreads();
    if (tid == 0) {
        partials[blockIdx.x] = make_float2(red[0] + red[1] + red[2] + red[3],
                                           red[4] + red[5] + red[6] + red[7]);
    }
}

__global__ __launch_bounds__(256) void finalize_kernel(
    const float4* __restrict__ partials4, float* __restrict__ o)
{
    const int tid = threadIdx.x;
    float box = 0.0f, cls = 0.0f;
    #pragma unroll
    for (int k = 0; k < 2; ++k) {                 // 1024 float2 = 512 float4
        const float4 p = partials4[tid + k * 256];
        box += p.x + p.z;
        cls += p.y + p.w;
    }
    #pragma unroll
    for (int off = 32; off > 0; off >>= 1) {
        box += __shfl_down(box, off);
        cls += __shfl_down(cls, off);
    }
    __shared__ float red[8];
    const int wv = tid >> 6, ln = tid & 63;
    if (ln == 0) { red[wv] = box; red[4 + wv] = cls; }
    __syncthreads();
    if (tid == 0) {
        const float boxT = red[0] + red[1] + red[2] + red[3];
        const float clsT = red[4] + red[5] + red[6] + red[7];
        o[0] = boxT + clsT;   // loss
        o[1] = clsT;          // loss_cls
        o[2] = boxT;          // loss_box
    }
}

extern "C" void kernel_launch(void* const* d_in, const int* in_sizes, int n_in,
                              void* d_out, int out_size, void* d_ws, size_t ws_size,
                              hipStream_t stream)
{
    const float* outp = (const float*)d_in[0];
    const float* tgt  = (const float*)d_in[1];
    float2* partials  = (float2*)d_ws;    // 1024 * 8 B, fully rewritten every call

    region_kernel<<<dim3(NBLK), dim3(TPB), 0, stream>>>(outp, tgt, partials);
    finalize_kernel<<<1, 256, 0, stream>>>((const float4*)partials, (float*)d_out);
}